// Round 8
// baseline (126.776 us; speedup 1.0000x reference)
//
#include <hip/hip_runtime.h>
#include <math.h>

#define CIN 3
#define DIN 16
#define HIN 128
#define WIN 128
#define COUT 24
#define HOUT 126
#define DOUT 14
#define HW (HIN * WIN)

using f16x8 = __attribute__((ext_vector_type(8))) _Float16;
using f32x4 = __attribute__((ext_vector_type(4))) float;

// Fragment-order im2col: per depth-slice slot, tuple (rel_h, kg, cl) at index
// rel_h*64 + kg*16 + cl holds the 8 halves k = kg*8+j of A-row px=cl for tile
// rel_h. A-load = ONE aligned ds_read_b128; builder write = ds_write_b128.
// 4-slot ring: compute reads slots dp..dp+2 while slot dp+3 is written.
__global__ __launch_bounds__(256, 2) void conv3d_min_softmax_mfma(
    const float* __restrict__ x,
    const float* __restrict__ wgt,
    const float* __restrict__ bias,
    float* __restrict__ out)
{
    __shared__ f16x8 imX[4 * 1024];   // 64 KB total, 16 KB per slot

    const int tid  = threadIdx.x;
    const int wv   = tid >> 6;
    const int lane = tid & 63;
    const int cl   = lane & 15;   // A: px-lane | B/C: co-lane
    const int kg   = lane >> 4;   // A/B: k-group | C: px-row-group

    const int wchunk = blockIdx.x;
    const int band   = blockIdx.y;
    const int b      = blockIdx.z;
    const int w0 = (wchunk < 7) ? wchunk * 16 : 110;   // overlap chunk: identical math, benign
    const int h0 = (band   < 7) ? band   * 16 : 110;

    const float* xb = x + (size_t)b * (CIN * DIN * HW);

    // ---- B-fragments (weights) in regs; k-order = kh*9 + ci*3 + kw; pads -> 0
    f16x8 bw[3][2];   // [kd][co-half]
    #pragma unroll
    for (int kd = 0; kd < 3; ++kd)
      #pragma unroll
      for (int hf = 0; hf < 2; ++hf)
        #pragma unroll
        for (int j = 0; j < 8; ++j) {
          int k  = kg * 8 + j;
          int co = hf * 16 + cl;
          float wvv = 0.f;
          if (k < 27 && co < 24) {
            int kh = k / 9, rem = k - kh * 9, ci = rem / 3, kw = rem - ci * 3;
            wvv = wgt[((co * 3 + ci) * 3 + kd) * 9 + kh * 3 + kw];
          }
          bw[kd][hf][j] = (_Float16)wvv;
        }

    const float bias0 = bias[cl];
    const float bias1 = (cl < 8) ? bias[16 + cl] : 0.f;

    // ---- builder: thread handles tuples idx = tid + it*256 (it = 0..3).
    // gof[it][j] = global offset within a slice for element j; -1 = zero-pad.
    int gof[4][8];
    #pragma unroll
    for (int it = 0; it < 4; ++it) {
      const int idx   = tid + it * 256;
      const int rel_h = idx >> 6;
      const int tkg   = (idx >> 4) & 3;
      const int tcl   = idx & 15;
      #pragma unroll
      for (int j = 0; j < 8; ++j) {
        const int k = tkg * 8 + j;
        int g = -1;
        if (k < 27) {
          int kh = k / 9, rem = k - kh * 9, ci = rem / 3, kw = rem - ci * 3;
          g = ci * (DIN * HW) + (h0 + rel_h + kh) * WIN + (w0 + kw + tcl);
        }
        gof[it][j] = g;
      }
    }

    // ---- preload slices 0..2 into slots 0..2
    #pragma unroll 1
    for (int s = 0; s < 3; ++s) {
      #pragma unroll
      for (int it = 0; it < 4; ++it) {
        f16x8 pk;
        #pragma unroll
        for (int j = 0; j < 8; ++j) {
          const int g = gof[it][j];
          float v = 0.f;
          if (g >= 0) v = xb[g + s * HW];
          pk[j] = (_Float16)v;
        }
        imX[s * 1024 + tid + it * 256] = pk;
      }
    }
    __syncthreads();

    // ---- main dp loop: min-accumulate conv(dp) in C-frag registers
    float mn[4][2][4];
    #pragma unroll
    for (int t = 0; t < 4; ++t)
      #pragma unroll
      for (int hf = 0; hf < 2; ++hf)
        #pragma unroll
        for (int j = 0; j < 4; ++j) mn[t][hf][j] = 3.4e38f;

    #pragma unroll 1
    for (int dp = 0; dp < DOUT; ++dp) {
      const int s = dp + 3;
      const bool doBuild = (s < DIN);

      // issue next-slice loads early (hide HBM under MFMA)
      float stv[4][8];
      if (doBuild) {
        #pragma unroll
        for (int it = 0; it < 4; ++it)
          #pragma unroll
          for (int j = 0; j < 8; ++j) {
            const int g = gof[it][j];
            stv[it][j] = (g >= 0) ? xb[g + s * HW] : 0.f;
          }
      }

      // compute: 4 tiles x (3 kd chained) x 2 co-halves
      #pragma unroll
      for (int t = 0; t < 4; ++t) {
        const int rel_h = wv * 4 + t;
        const int tb = rel_h * 64 + kg * 16 + cl;

        f16x8 A0 = imX[((dp + 0) & 3) * 1024 + tb];
        f16x8 A1 = imX[((dp + 1) & 3) * 1024 + tb];
        f16x8 A2 = imX[((dp + 2) & 3) * 1024 + tb];

        f32x4 z = {0.f, 0.f, 0.f, 0.f};
        f32x4 acc0 = __builtin_amdgcn_mfma_f32_16x16x32_f16(A0, bw[0][0], z, 0, 0, 0);
        f32x4 acc1 = __builtin_amdgcn_mfma_f32_16x16x32_f16(A0, bw[0][1], z, 0, 0, 0);
        acc0 = __builtin_amdgcn_mfma_f32_16x16x32_f16(A1, bw[1][0], acc0, 0, 0, 0);
        acc1 = __builtin_amdgcn_mfma_f32_16x16x32_f16(A1, bw[1][1], acc1, 0, 0, 0);
        acc0 = __builtin_amdgcn_mfma_f32_16x16x32_f16(A2, bw[2][0], acc0, 0, 0, 0);
        acc1 = __builtin_amdgcn_mfma_f32_16x16x32_f16(A2, bw[2][1], acc1, 0, 0, 0);

        #pragma unroll
        for (int j = 0; j < 4; ++j) {
          mn[t][0][j] = fminf(mn[t][0][j], acc0[j]);
          mn[t][1][j] = fminf(mn[t][1][j], acc1[j]);
        }
      }

      // pack + write staged slice (slot dp+3 disjoint from slots dp..dp+2)
      if (doBuild) {
        #pragma unroll
        for (int it = 0; it < 4; ++it) {
          f16x8 pk;
          #pragma unroll
          for (int j = 0; j < 8; ++j) pk[j] = (_Float16)stv[it][j];
          imX[(s & 3) * 1024 + tid + it * 256] = pk;
        }
      }
      __syncthreads();
    }

    // ---- fused bias + softmax over channels (cross-lane over 16-lane group)
    float* ob = out + (size_t)b * COUT * HOUT * HOUT;
    #pragma unroll
    for (int t = 0; t < 4; ++t) {
      const int h = h0 + wv * 4 + t;
      #pragma unroll
      for (int j = 0; j < 4; ++j) {
        float v0 = mn[t][0][j] + bias0;
        float v1 = (cl < 8) ? (mn[t][1][j] + bias1) : -3.4e38f;
        float mx = fmaxf(v0, v1);
        #pragma unroll
        for (int msk = 1; msk < 16; msk <<= 1)
          mx = fmaxf(mx, __shfl_xor(mx, msk));
        float e0 = __expf(v0 - mx);
        float e1 = (cl < 8) ? __expf(v1 - mx) : 0.f;
        float sm = e0 + e1;
        #pragma unroll
        for (int msk = 1; msk < 16; msk <<= 1)
          sm += __shfl_xor(sm, msk);
        float r = 1.f / sm;
        const int w = w0 + kg * 4 + j;
        ob[((size_t)cl * HOUT + h) * HOUT + w] = e0 * r;
        if (cl < 8)
          ob[((size_t)(16 + cl) * HOUT + h) * HOUT + w] = e1 * r;
      }
    }
}

extern "C" void kernel_launch(void* const* d_in, const int* in_sizes, int n_in,
                              void* d_out, int out_size, void* d_ws, size_t ws_size,
                              hipStream_t stream) {
    const float* x    = (const float*)d_in[0];
    const float* wgt  = (const float*)d_in[1];
    const float* bias = (const float*)d_in[2];
    float* out        = (float*)d_out;

    dim3 grid(8, 8, 16);   // (wchunk, band, b)
    dim3 block(256);
    conv3d_min_softmax_mfma<<<grid, block, 0, stream>>>(x, wgt, bias, out);
}